// Round 2
// baseline (576.271 us; speedup 1.0000x reference)
//
#include <hip/hip_runtime.h>
#include <math.h>

#define BGR 64          // graphs
#define N0 512          // nodes/graph at level 1
#define E_TOT (BGR*N0*16)
#define EPG 8192        // edge slots per graph, fixed across levels
#define EIT 16          // EPG / 512 threads
#define HID 128

// LDS h-tile index: row-major [row][8 float4] with XOR swizzle to break the
// 8-way bank conflict of the pure stride-8 layout (row*32 floats ≡ bank 0).
#define XLI(row,l4) (((row)<<3) | (((l4) ^ (row)) & 7))

// ---- XCD heuristic: blockIdx % 8 -> XCD; graph g pinned to XCD g mod-class.
// The 4 sub-blocks of a graph share blockIdx%64 -> same XCD slot (L2 local).

// Agent-scope (L1-bypassing) load — ONLY for the canonical sub-0 csr copy
// that is re-read across levels by remote blocks (stale-L1 hazard).
__device__ __forceinline__ int2 ldcoh(const int2* p){
  unsigned long long v = __hip_atomic_load(
      (const unsigned long long*)p, __ATOMIC_RELAXED, __HIP_MEMORY_SCOPE_AGENT);
  int2 r; r.x = (int)(unsigned int)v; r.y = (int)(unsigned int)(v >> 32);
  return r;
}

template<bool COH>
__device__ __forceinline__ int2 lde(const int2* p){
  if (COH) return ldcoh(p);
  return *p;
}

// scalar score-GCN edge sum (hloc in LDS); start is absolute into csr
template<bool COH>
__device__ __forceinline__ float score_edges(const int2* __restrict__ csr,
    int start, int c, const float* hloc, int gbase){
  float a = 0.f; int j = 0;
  for (; j + 4 <= c; j += 4){
    int2 e0 = lde<COH>(csr+start+j),   e1 = lde<COH>(csr+start+j+1);
    int2 e2 = lde<COH>(csr+start+j+2), e3 = lde<COH>(csr+start+j+3);
    a += __int_as_float(e0.y)*hloc[e0.x - gbase]
       + __int_as_float(e1.y)*hloc[e1.x - gbase]
       + __int_as_float(e2.y)*hloc[e2.x - gbase]
       + __int_as_float(e3.y)*hloc[e3.x - gbase];
  }
  for (; j < c; j++){
    int2 e = lde<COH>(csr+start+j);
    a += __int_as_float(e.y)*hloc[e.x - gbase];
  }
  return a;
}

// full GCN row (32-feat slice): edge agg + self + bias + relu. Plain loads:
// csr here is always the block's PRIVATE copy (same-CU RAW is coherent).
__device__ __forceinline__ float4 gcn_row(const int2* __restrict__ csr,
    int start, int c, const float4* xl4, int gbase, int l, int row,
    float dd, float4 bb){
  float4 acc = make_float4(0.f,0.f,0.f,0.f);
  int j = 0;
  for (; j + 4 <= c; j += 4){
    int2 e0 = csr[start+j],   e1 = csr[start+j+1];
    int2 e2 = csr[start+j+2], e3 = csr[start+j+3];
    float4 h0 = xl4[XLI(e0.x - gbase, l)];
    float4 h1 = xl4[XLI(e1.x - gbase, l)];
    float4 h2 = xl4[XLI(e2.x - gbase, l)];
    float4 h3 = xl4[XLI(e3.x - gbase, l)];
    float w0 = __int_as_float(e0.y), w1 = __int_as_float(e1.y);
    float w2 = __int_as_float(e2.y), w3 = __int_as_float(e3.y);
    acc.x += w0*h0.x + w1*h1.x + w2*h2.x + w3*h3.x;
    acc.y += w0*h0.y + w1*h1.y + w2*h2.y + w3*h3.y;
    acc.z += w0*h0.z + w1*h1.z + w2*h2.z + w3*h3.z;
    acc.w += w0*h0.w + w1*h1.w + w2*h2.w + w3*h3.w;
  }
  for (; j < c; j++){
    int2 e = csr[start + j];
    float wgt = __int_as_float(e.y);
    float4 hv = xl4[XLI(e.x - gbase, l)];
    acc.x += wgt*hv.x; acc.y += wgt*hv.y; acc.z += wgt*hv.z; acc.w += wgt*hv.w;
  }
  float4 hs = xl4[XLI(row, l)];
  float4 v;
  v.x = fmaxf(acc.x + hs.x*dd + bb.x, 0.f);
  v.y = fmaxf(acc.y + hs.y*dd + bb.y, 0.f);
  v.z = fmaxf(acc.z + hs.z*dd + bb.z, 0.f);
  v.w = fmaxf(acc.w + hs.w*dd + bb.w, 0.f);
  return v;
}

// hybrid shfl/LDS bitonic (descending, idx tie-break)
__device__ __forceinline__ void bitonic_sort(float* sv, int* si, float v, int idx,
                                             int t, int nper, bool act){
  for (int kk = 2; kk <= nper; kk <<= 1){
    for (int jj = kk >> 1; jj > 0; jj >>= 1){
      if (jj >= 64){
        if (act){ sv[t] = v; si[t] = idx; }
        __syncthreads();
        if (act){
          int p = t ^ jj;
          float pv = sv[p]; int pi = si[p];
          bool amLower = (t & jj) == 0;
          bool dirDesc = (t & kk) == 0;
          bool betterMine = (v > pv) || (v == pv && idx < pi);
          if ((amLower == dirDesc) != betterMine){ v = pv; idx = pi; }
        }
        __syncthreads();
      } else if (act){
        float pv = __shfl_xor(v, jj);
        int   pi = __shfl_xor(idx, jj);
        bool amLower = (t & jj) == 0;
        bool dirDesc = (t & kk) == 0;
        bool betterMine = (v > pv) || (v == pv && idx < pi);
        if ((amLower == dirDesc) != betterMine){ v = pv; idx = pi; }
      }
    }
  }
  if (act){ sv[t] = v; si[t] = idx; }
  __syncthreads();
}

// relabel: read edge list at esrc+sbase, write new list to edst+dbase and
// CSR (+weights) to csr+cbase. Topology (rpl/cntl/dl) -> LDS. Deterministic
// except csr intra-bucket order (block-private, never shared for scoring).
__device__ __forceinline__ void relabel4(const int2* __restrict__ esrc, int sbase,
    int2* __restrict__ edst, int dbase, int2* __restrict__ csr, int cbase,
    const int* si, int* map_, int* sb, int* cur, float* dl, int* rpl, int* cntl,
    int t, int nper, int k, int gbase){
  if (t < nper) map_[t] = -1;
  if (t < k) sb[t] = 0;
  __syncthreads();
  if (t < k) map_[si[t]] = t;
  __syncthreads();
  int2 ebuf[EIT];
  #pragma unroll
  for (int it = 0; it < EIT; it++){
    int slot = it*512 + t;
    int2 e = esrc[sbase + slot];
    int2 ne = make_int2(-1, 0);
    if (e.x >= 0){
      int ns = map_[e.x - gbase], nd = map_[e.y - gbase];
      if (ns >= 0 && nd >= 0){
        ne = make_int2(gbase + ns, gbase + nd);
        atomicAdd(&sb[nd], 1);
      }
    }
    ebuf[it] = ne;
    edst[dbase + slot] = ne;
  }
  __syncthreads();
  int vdeg = (t < k) ? sb[t] : 0;
  for (int off = 1; off < k; off <<= 1){
    int add = (t >= off && t < k) ? sb[t-off] : 0;
    __syncthreads();
    if (t < k) sb[t] += add;
    __syncthreads();
  }
  if (t < k){
    int excl = sb[t] - vdeg;
    rpl[t] = cbase + excl;
    cntl[t] = vdeg;
    cur[t] = excl;
    float dv = rsqrtf((float)vdeg + 1.f);
    dl[t] = dv;
  }
  __syncthreads();
  #pragma unroll
  for (int it = 0; it < EIT; it++){
    int2 e = ebuf[it];
    if (e.x >= 0){
      int sl = e.x - gbase, dc = e.y - gbase;
      int pos = atomicAdd(&cur[dc], 1);
      csr[cbase + pos] = make_int2(e.x, __float_as_int(dl[sl]*dl[dc]));
    }
  }
  __syncthreads();
}

// h-slice = x(global, full feats) @ W[:, s*32 .. s*32+31]; NT = nodes/64.
// i-ascending accumulation, same per-output order as previous rounds.
template<int NT>
__device__ __forceinline__ void gemm_slice(const float* __restrict__ xg,
    const float* __restrict__ W, float4* xl4, int t, int s){
  int f4 = t & 7, ng = t >> 3;
  const float* Wb = W + s*32 + f4*4;
  float4 acc[NT];
  #pragma unroll
  for (int c = 0; c < NT; c++) acc[c] = make_float4(0.f,0.f,0.f,0.f);
  for (int i = 0; i < HID; i += 4){
    float4 w0 = *(const float4*)(Wb + (i+0)*HID);
    float4 w1 = *(const float4*)(Wb + (i+1)*HID);
    float4 w2 = *(const float4*)(Wb + (i+2)*HID);
    float4 w3 = *(const float4*)(Wb + (i+3)*HID);
    #pragma unroll
    for (int c = 0; c < NT; c++){
      float4 xv = *(const float4*)(xg + (ng + 64*c)*HID + i);
      acc[c].x += xv.x*w0.x; acc[c].x += xv.y*w1.x;
      acc[c].x += xv.z*w2.x; acc[c].x += xv.w*w3.x;
      acc[c].y += xv.x*w0.y; acc[c].y += xv.y*w1.y;
      acc[c].y += xv.z*w2.y; acc[c].y += xv.w*w3.y;
      acc[c].z += xv.x*w0.z; acc[c].z += xv.y*w1.z;
      acc[c].z += xv.z*w2.z; acc[c].z += xv.w*w3.z;
      acc[c].w += xv.x*w0.w; acc[c].w += xv.y*w1.w;
      acc[c].w += xv.z*w2.w; acc[c].w += xv.w*w3.w;
    }
  }
  #pragma unroll
  for (int c = 0; c < NT; c++) xl4[XLI(ng + 64*c, f4)] = acc[c];
}

// readout (max || mean) over rows [0,R) of the 32-feat LDS slice -> zsl[64]
__device__ __forceinline__ void zacc_pass(const float* xl, float zp[][8][32],
    float* zsl, int R, int init, int t){
  if (t < 256){
    int q = t >> 5, f = t & 31;
    float m = -INFINITY, sm = 0.f;
    for (int r = q; r < R; r += 8){
      float vv = xl[XLI(r, f >> 2)*4 + (f & 3)];
      m = fmaxf(m, vv); sm += vv;
    }
    zp[0][q][f] = m; zp[1][q][f] = sm;
  }
  __syncthreads();
  if (t < 32){
    float m = zp[0][0][t], sm = zp[1][0][t];
    #pragma unroll
    for (int q = 1; q < 8; q++){ m = fmaxf(m, zp[0][q][t]); sm += zp[1][q][t]; }
    float ki = 1.f/(float)R;
    if (init){ zsl[t] = m; zsl[32+t] = sm*ki; }
    else     { zsl[t] += m; zsl[32+t] += sm*ki; }
  }
  __syncthreads();
}

// 4-block-per-graph barrier: release writes to L2, arrive, spin, invalidate L1.
__device__ __forceinline__ void gsync(int* c, int t){
  __threadfence();
  __syncthreads();
  if (t == 0){
    __hip_atomic_fetch_add(c, 1, __ATOMIC_ACQ_REL, __HIP_MEMORY_SCOPE_AGENT);
    while (__hip_atomic_load(c, __ATOMIC_ACQUIRE, __HIP_MEMORY_SCOPE_AGENT) < 4)
      __builtin_amdgcn_s_sleep(4);
  }
  __syncthreads();
  __threadfence();
}

// Per-graph level-1 topology (+ zero the sync counters for k_tail4)
__global__ __launch_bounds__(512) void k_topo0(
    const int* __restrict__ s0, const int* __restrict__ d0,
    int2* __restrict__ edges, int* __restrict__ cnt, int* __restrict__ rowptr,
    float* __restrict__ dinv, int2* __restrict__ csr, int* __restrict__ syncc){
  __shared__ int   deg[512];
  __shared__ int   sb[512];
  __shared__ int   cur[512];
  __shared__ float dl[512];
  int g = (blockIdx.x & 7)*8 + (blockIdx.x >> 3);
  int t = threadIdx.x;
  int gbase = g*N0, ebase = g*EPG;
  if (t < 8) syncc[g*8 + t] = 0;
  deg[t] = 0;
  __syncthreads();
  int2 ebuf[EIT];
  #pragma unroll
  for (int it = 0; it < EIT; it++){
    int i = ebase + it*512 + t;
    int2 e = make_int2(s0[i], d0[i]);
    ebuf[it] = e;
    edges[i] = e;
    atomicAdd(&deg[e.y - gbase], 1);
  }
  __syncthreads();
  int vdeg = deg[t];
  sb[t] = vdeg; __syncthreads();
  for (int off = 1; off < 512; off <<= 1){
    int add = (t >= off) ? sb[t-off] : 0;
    __syncthreads(); sb[t] += add; __syncthreads();
  }
  int excl = sb[t] - vdeg;
  rowptr[gbase + t] = ebase + excl;
  cnt[gbase + t] = vdeg;
  cur[t] = excl;
  float dv = rsqrtf((float)vdeg + 1.f);
  dl[t] = dv;
  dinv[gbase + t] = dv;
  __syncthreads();
  #pragma unroll
  for (int it = 0; it < EIT; it++){
    int2 e = ebuf[it];
    int sl = e.x - gbase, dc = e.y - gbase;
    int pos = atomicAdd(&cur[dc], 1);
    csr[ebase + pos] = make_int2(e.x, __float_as_int(dl[sl]*dl[dc]));
  }
}

// Level-1 fused GEMM+gather (unchanged)
__global__ __launch_bounds__(512) void k_l1_fused(
    const float* __restrict__ x, const float* __restrict__ W1,
    const int2* __restrict__ csr, const int* __restrict__ rowptr,
    const int* __restrict__ cnt, const float* __restrict__ dinv,
    const float* __restrict__ b1, const float* __restrict__ Wp,
    float4* __restrict__ gout4, float* __restrict__ hp_part){
  extern __shared__ float hl[];   // 512 nodes x 32 feats = 64 KB
  int b = blockIdx.x;
  int xcd = b & 7, idx = b >> 3;
  int graph = xcd*8 + (idx >> 3);
  int sub = idx & 7;
  int qf = sub >> 1, half = sub & 1;
  int t = threadIdx.x;
  int gbase = graph*N0;
  int fp = t & 31;
  int f = qf*32 + fp;
  float wcol[10];
  #pragma unroll
  for (int k = 0; k < 10; k++) wcol[k] = W1[k*HID + f];
  for (int n = t >> 5; n < N0; n += 16){
    const float* xr = x + (gbase + n)*10;
    float acc = 0.f;
    #pragma unroll
    for (int k = 0; k < 10; k++) acc += xr[k]*wcol[k];
    hl[n*32 + fp] = acc;
  }
  __syncthreads();
  const float4* hl4 = (const float4*)hl;
  int l = t & 7, grp = t >> 3;
  float4 bb = ((const float4*)b1)[qf*8 + l];
  float4 wp = ((const float4*)Wp)[qf*8 + l];
  int n0 = half*256;
  for (int nl = n0 + grp; nl < n0 + 256; nl += 64){
    int node = gbase + nl;
    int start = rowptr[node], c = cnt[node];
    float4 acc = make_float4(0.f,0.f,0.f,0.f);
    int j = 0;
    for (; j + 4 <= c; j += 4){
      int2 e0 = csr[start+j],   e1 = csr[start+j+1];
      int2 e2 = csr[start+j+2], e3 = csr[start+j+3];
      float4 h0 = hl4[(e0.x - gbase)*8 + l];
      float4 h1 = hl4[(e1.x - gbase)*8 + l];
      float4 h2 = hl4[(e2.x - gbase)*8 + l];
      float4 h3 = hl4[(e3.x - gbase)*8 + l];
      float w0 = __int_as_float(e0.y), w1 = __int_as_float(e1.y);
      float w2 = __int_as_float(e2.y), w3 = __int_as_float(e3.y);
      acc.x += w0*h0.x + w1*h1.x + w2*h2.x + w3*h3.x;
      acc.y += w0*h0.y + w1*h1.y + w2*h2.y + w3*h3.y;
      acc.z += w0*h0.z + w1*h1.z + w2*h2.z + w3*h3.z;
      acc.w += w0*h0.w + w1*h1.w + w2*h2.w + w3*h3.w;
    }
    for (; j < c; j++){
      int2 e = csr[start + j];
      float wgt = __int_as_float(e.y);
      float4 hv = hl4[(e.x - gbase)*8 + l];
      acc.x += wgt*hv.x; acc.y += wgt*hv.y; acc.z += wgt*hv.z; acc.w += wgt*hv.w;
    }
    float di = dinv[node], dd = di*di;
    float4 hs = hl4[nl*8 + l];
    float4 v;
    v.x = fmaxf(acc.x + hs.x*dd + bb.x, 0.f);
    v.y = fmaxf(acc.y + hs.y*dd + bb.y, 0.f);
    v.z = fmaxf(acc.z + hs.z*dd + bb.z, 0.f);
    v.w = fmaxf(acc.w + hs.w*dd + bb.w, 0.f);
    gout4[node*32 + qf*8 + l] = v;
    float contrib = v.x*wp.x + v.y*wp.y + v.z*wp.z + v.w*wp.w;
    #pragma unroll
    for (int off = 4; off; off >>= 1) contrib += __shfl_down(contrib, off, 8);
    if (l == 0) hp_part[qf*32768 + node] = contrib;
  }
}

// Tail, 4 blocks per graph (grid 256 = full machine), feature-split by 32.
// Duplicated: score/sort/relabel (deterministic; scores read canonical sub-0
// csr). Feature-parallel: pool, GEMM, gather, recompute, readout. Cross-block
// exchange (x2g/x3g, hp partials, z slices) via global + spin barriers; the
// 4 sub-blocks of a graph are always co-resident (grid <= capacity).
__global__ __launch_bounds__(512) void k_tail4(
    const float4* __restrict__ gout4, const float* __restrict__ hppt,
    const int2* __restrict__ edges1, const int2* __restrict__ csr1,
    const int* __restrict__ rowptr1, const int* __restrict__ cnt1,
    const float* __restrict__ dinv1,
    int2* __restrict__ edges4, int2* __restrict__ csr4,
    float* __restrict__ x2g, float* __restrict__ x3g,
    float* __restrict__ hp2, float* __restrict__ hp3,
    float* __restrict__ zg, int* __restrict__ syncc,
    const float* __restrict__ bp,
    const float* __restrict__ W2, const float* __restrict__ b2,
    const float* __restrict__ W3, const float* __restrict__ b3,
    const float* __restrict__ Wp,
    const float* __restrict__ L1W, const float* __restrict__ L1b,
    const float* __restrict__ L2W, const float* __restrict__ L2b,
    float* __restrict__ out){
  __shared__ float xl[256*32];            // 32 KB feature-slice tile
  __shared__ float sv[512];
  __shared__ int   si[512];
  __shared__ float hpl[512];
  __shared__ int   map_[512];
  __shared__ int   sb[512];
  __shared__ int   cur[256];
  __shared__ float dl[256];
  __shared__ int   rpl[256];
  __shared__ int   cntl[256];
  __shared__ float zp[2][8][32];
  __shared__ float zsl[64];
  __shared__ float red[2];

  int b = blockIdx.x;
  int jb = b & 63, s = b >> 6;            // jb -> graph, s -> feature slice
  int g = (jb & 7)*8 + (jb >> 3);
  int t = threadIdx.x;
  int gbase = g*N0;
  int ebase  = (s*BGR + g)*EPG;           // private topo region
  int ebase0 = g*EPG;                     // canonical sub-0 region (scores)
  int l = t & 7, grp = t >> 3;
  float4* xl4 = (float4*)xl;
  float bp0 = bp[0];
  int* sc = syncc + g*8;

  // ================= M1: score + sort (duplicated) =================
  {
    int node = gbase + t;
    hpl[t] = hppt[node] + hppt[32768+node] + hppt[65536+node] + hppt[98304+node];
  }
  __syncthreads();
  {
    int start = rowptr1[gbase + t], c = cnt1[gbase + t];
    float a = score_edges<false>(csr1, start, c, hpl, gbase);
    float di = dinv1[gbase + t];
    float v = tanhf(a + hpl[t]*di*di + bp0);
    bitonic_sort(sv, si, v, t, t, 512, true);
  }
  // pool1: own 32-feat slice of 256 selected rows -> LDS + x2g
  #pragma unroll
  for (int p = 0; p < 4; p++){
    int jr = grp + 64*p;
    float val = sv[jr]; int row = si[jr];
    float4 hv = gout4[(gbase + row)*32 + s*8 + l];
    float4 o = make_float4(hv.x*val, hv.y*val, hv.z*val, hv.w*val);
    xl4[XLI(jr, l)] = o;
    *(float4*)(x2g + (g*256 + jr)*HID + s*32 + l*4) = o;
  }
  __syncthreads();
  zacc_pass(xl, zp, zsl, 256, 1, t);
  relabel4(edges1, g*EPG, edges4, ebase, csr4, ebase,
           si, map_, sb, cur, dl, rpl, cntl, t, 512, 256, gbase);
  gsync(sc + 0, t);                       // x2g complete

  // ================= level 2: GEMM slice + gather hp =================
  gemm_slice<4>(x2g + g*256*HID, W2, xl4, t, s);
  __syncthreads();
  {
    float4 bb = ((const float4*)b2)[s*8 + l];
    float4 wp = ((const float4*)Wp)[s*8 + l];
    #pragma unroll
    for (int p = 0; p < 4; p++){
      int row = grp + 64*p;
      float dd = dl[row]*dl[row];
      float4 v = gcn_row(csr4, rpl[row], cntl[row], xl4, gbase, l, row, dd, bb);
      float contrib = v.x*wp.x + v.y*wp.y + v.z*wp.z + v.w*wp.w;
      #pragma unroll
      for (int off = 4; off; off >>= 1) contrib += __shfl_down(contrib, off, 8);
      if (l == 0) hp2[s*32768 + gbase + row] = contrib;
    }
  }
  gsync(sc + 1, t);                       // hp2 complete

  // ================= M2: score+sort, recompute 128 rows, relabel ==========
  if (t < 256){
    int node = gbase + t;
    hpl[t] = hp2[node] + hp2[32768+node] + hp2[65536+node] + hp2[98304+node];
  }
  __syncthreads();
  {
    float v = 0.f;
    if (t < 256){
      int st0 = rpl[t] - ebase + ebase0;  // same offsets, canonical copy
      float a = score_edges<true>(csr4, st0, cntl[t], hpl, gbase);
      v = tanhf(a + hpl[t]*dl[t]*dl[t] + bp0);
    }
    bitonic_sort(sv, si, v, t, t, 256, t < 256);
  }
  {
    float4 bb = ((const float4*)b2)[s*8 + l];
    float4 ov[2];
    #pragma unroll
    for (int p = 0; p < 2; p++){
      int jr = grp + 64*p;
      float val = sv[jr]; int row = si[jr];
      float dd = dl[row]*dl[row];
      float4 v = gcn_row(csr4, rpl[row], cntl[row], xl4, gbase, l, row, dd, bb);
      ov[p] = make_float4(v.x*val, v.y*val, v.z*val, v.w*val);
      *(float4*)(x3g + (g*128 + jr)*HID + s*32 + l*4) = ov[p];
    }
    __syncthreads();                      // all h2 reads done
    #pragma unroll
    for (int p = 0; p < 2; p++) xl4[XLI(grp + 64*p, l)] = ov[p];
  }
  __syncthreads();
  zacc_pass(xl, zp, zsl, 128, 0, t);
  relabel4(edges4, ebase, edges4, ebase, csr4, ebase,
           si, map_, sb, cur, dl, rpl, cntl, t, 256, 128, gbase);
  gsync(sc + 2, t);                       // x3g complete

  // ================= level 3: GEMM slice + gather hp =================
  gemm_slice<2>(x3g + g*128*HID, W3, xl4, t, s);
  __syncthreads();
  {
    float4 bb = ((const float4*)b3)[s*8 + l];
    float4 wp = ((const float4*)Wp)[s*8 + l];
    #pragma unroll
    for (int p = 0; p < 2; p++){
      int row = grp + 64*p;
      float dd = dl[row]*dl[row];
      float4 v = gcn_row(csr4, rpl[row], cntl[row], xl4, gbase, l, row, dd, bb);
      float contrib = v.x*wp.x + v.y*wp.y + v.z*wp.z + v.w*wp.w;
      #pragma unroll
      for (int off = 4; off; off >>= 1) contrib += __shfl_down(contrib, off, 8);
      if (l == 0) hp3[s*32768 + gbase + row] = contrib;
    }
  }
  gsync(sc + 3, t);                       // hp3 complete

  // ================= M3: score+sort, recompute 64 rows, readout ==========
  if (t < 128){
    int node = gbase + t;
    hpl[t] = hp3[node] + hp3[32768+node] + hp3[65536+node] + hp3[98304+node];
  }
  __syncthreads();
  {
    float v = 0.f;
    if (t < 128){
      int st0 = rpl[t] - ebase + ebase0;
      float a = score_edges<true>(csr4, st0, cntl[t], hpl, gbase);
      v = tanhf(a + hpl[t]*dl[t]*dl[t] + bp0);
    }
    bitonic_sort(sv, si, v, t, t, 128, t < 128);
  }
  {
    float4 bb = ((const float4*)b3)[s*8 + l];
    int jr = grp;                         // 64 rows x 8 lanes = 512 threads
    float val = sv[jr]; int row = si[jr];
    float dd = dl[row]*dl[row];
    float4 v = gcn_row(csr4, rpl[row], cntl[row], xl4, gbase, l, row, dd, bb);
    float4 ov = make_float4(v.x*val, v.y*val, v.z*val, v.w*val);
    __syncthreads();                      // all h3 reads done
    xl4[XLI(jr, l)] = ov;
  }
  __syncthreads();
  zacc_pass(xl, zp, zsl, 64, 0, t);
  if (t < 64){
    int pos = (t < 32) ? (s*32 + t) : (96 + s*32 + t);  // [max32 || mean32]
    zg[g*256 + pos] = zsl[t];
  }
  // final barrier: non-canonical blocks arrive and exit
  __threadfence();
  __syncthreads();
  if (t == 0)
    __hip_atomic_fetch_add(sc + 4, 1, __ATOMIC_ACQ_REL, __HIP_MEMORY_SCOPE_AGENT);
  if (s != 0) return;
  if (t == 0){
    while (__hip_atomic_load(sc + 4, __ATOMIC_ACQUIRE, __HIP_MEMORY_SCOPE_AGENT) < 4)
      __builtin_amdgcn_s_sleep(4);
  }
  __syncthreads();
  __threadfence();

  // ================= MLP + log_softmax (sub-0 only) =================
  if (t < 256) hpl[t] = zg[g*256 + t];
  __syncthreads();
  if (t < 128){
    float a = L1b[t];
    for (int i = 0; i < 256; i++) a += hpl[i]*L1W[i*128 + t];
    sv[t] = fmaxf(a, 0.f);
  }
  __syncthreads();
  if (t < 64){
    float a = L2b[t];
    for (int i = 0; i < 128; i++) a += sv[i]*L2W[i*64 + t];
    hpl[256 + t] = fmaxf(a, 0.f);
  }
  __syncthreads();
  if (t == 0){
    float mxv = -INFINITY;
    for (int i = 0; i < 64; i++) mxv = fmaxf(mxv, hpl[256+i]);
    float sx = 0.f;
    for (int i = 0; i < 64; i++) sx += expf(hpl[256+i] - mxv);
    red[0] = mxv; red[1] = logf(sx);
  }
  __syncthreads();
  if (t < 64) out[g*64 + t] = hpl[256+t] - red[0] - red[1];
}

extern "C" void kernel_launch(void* const* d_in, const int* in_sizes, int n_in,
                              void* d_out, int out_size, void* d_ws, size_t ws_size,
                              hipStream_t stream){
  (void)in_sizes; (void)n_in; (void)out_size; (void)ws_size;
  const float* x0  = (const float*)d_in[0];
  const int*   s0  = (const int*)  d_in[1];
  const int*   d0  = (const int*)  d_in[2];
  const float* W1  = (const float*)d_in[3];  const float* b1 = (const float*)d_in[4];
  const float* W2  = (const float*)d_in[5];  const float* b2 = (const float*)d_in[6];
  const float* W3  = (const float*)d_in[7];  const float* b3 = (const float*)d_in[8];
  const float* Wp  = (const float*)d_in[9];  const float* bp = (const float*)d_in[10];
  const float* L1W = (const float*)d_in[11]; const float* L1b = (const float*)d_in[12];
  const float* L2W = (const float*)d_in[13]; const float* L2b = (const float*)d_in[14];
  float* out = (float*)d_out;

  // workspace layout (floats; ~73 MB, ws is 256 MB+ per harness fill size)
  float* w = (float*)d_ws;
  float* gout  = w; w += 32768*HID;          // level-1 GCN output
  float* dinvv = w; w += 32768;
  float* hppt  = w; w += 4*32768;            // L1 hp quarter-partials
  float* x2g   = w; w += BGR*256*HID;        // pooled x, level 2 (full feats)
  float* x3g   = w; w += BGR*128*HID;        // pooled x, level 3
  float* hp2   = w; w += 4*32768;            // level-2 hp slice-partials
  float* hp3   = w; w += 4*32768;
  float* zg    = w; w += BGR*256;            // readout z
  int*  cnt1    = (int*)w; w += 32768;
  int*  rowptr1 = (int*)w; w += 32768;
  int*  syncc   = (int*)w; w += 1024;        // 64 graphs x 8 phase counters
  int2* edges1 = (int2*)w; w += 2*E_TOT;     // level-1 edge list (shared RO)
  int2* csr1   = (int2*)w; w += 2*E_TOT;     // level-1 CSR (shared RO)
  int2* edges4 = (int2*)w; w += 8*E_TOT;     // 4 private copies, levels 2/3
  int2* csr4   = (int2*)w; w += 8*E_TOT;     // 4 private copies, levels 2/3

  k_topo0<<<BGR, 512, 0, stream>>>(s0, d0, edges1, cnt1, rowptr1, dinvv, csr1,
                                   syncc);
  k_l1_fused<<<512, 512, 65536, stream>>>(x0, W1, csr1, rowptr1, cnt1, dinvv,
                                          b1, Wp, (float4*)gout, hppt);
  k_tail4<<<4*BGR, 512, 0, stream>>>((const float4*)gout, hppt,
                                     edges1, csr1, rowptr1, cnt1, dinvv,
                                     edges4, csr4, x2g, x3g, hp2, hp3, zg,
                                     syncc, bp, W2, b2, W3, b3, Wp,
                                     L1W, L1b, L2W, L2b, out);
}

// Round 3
// 242.975 us; speedup vs baseline: 2.3717x; 2.3717x over previous
//
#include <hip/hip_runtime.h>
#include <math.h>

#define BGR 64          // graphs
#define N0 512          // nodes/graph at level 1
#define E_TOT (BGR*N0*16)
#define EPG 8192        // edge slots per graph, fixed across levels
#define EIT 16          // EPG / 512 threads (topo0)
#define HID 128

// ---- XCD heuristic: blockIdx % 8 -> XCD; graph g pinned to XCD g/8.

// Per-graph level-1 topology: edge copy + degree (LDS atomics) + shfl-scan +
// dinv + CSR fill (edges register-buffered). 512 threads (scatter order kept
// identical to the validated round-0 version).
__global__ __launch_bounds__(512) void k_topo0(
    const int* __restrict__ s0, const int* __restrict__ d0,
    int2* __restrict__ edges, int* __restrict__ cnt, int* __restrict__ rowptr,
    float* __restrict__ dinv, int2* __restrict__ csr){
  __shared__ int   deg[512];
  __shared__ int   cur[512];
  __shared__ float dl[512];
  __shared__ int   wsum[8];
  int g = (blockIdx.x & 7)*8 + (blockIdx.x >> 3);
  int t = threadIdx.x;
  int gbase = g*N0, ebase = g*EPG;
  deg[t] = 0;
  __syncthreads();
  int2 ebuf[EIT];
  #pragma unroll
  for (int it = 0; it < EIT; it++){
    int i = ebase + it*512 + t;
    int2 e = make_int2(s0[i], d0[i]);
    ebuf[it] = e;
    edges[i] = e;
    atomicAdd(&deg[e.y - gbase], 1);
  }
  __syncthreads();
  int vdeg = deg[t];
  // shfl inclusive scan (bit-identical excl values, 1 barrier instead of 18)
  int lane = t & 63, wid = t >> 6;
  int x = vdeg;
  #pragma unroll
  for (int off = 1; off < 64; off <<= 1){
    int y = __shfl_up(x, off);
    if (lane >= off) x += y;
  }
  if (lane == 63) wsum[wid] = x;
  __syncthreads();
  int prefix = 0;
  #pragma unroll
  for (int wj = 0; wj < 8; wj++) prefix += (wj < wid) ? wsum[wj] : 0;
  int excl = x + prefix - vdeg;
  rowptr[gbase + t] = ebase + excl;
  cnt[gbase + t] = vdeg;
  cur[t] = excl;
  float dv = rsqrtf((float)vdeg + 1.f);
  dl[t] = dv;
  dinv[gbase + t] = dv;
  __syncthreads();
  #pragma unroll
  for (int it = 0; it < EIT; it++){
    int2 e = ebuf[it];
    int sl = e.x - gbase, dc = e.y - gbase;
    int pos = atomicAdd(&cur[dc], 1);
    csr[ebase + pos] = make_int2(e.x, __float_as_int(dl[sl]*dl[dc]));
  }
}

// Level-1 fused GEMM+gather (round-0 verbatim): block = (graph, feat-quarter,
// node-half); grid 512 (2 blocks/CU).
__global__ __launch_bounds__(512) void k_l1_fused(
    const float* __restrict__ x, const float* __restrict__ W1,
    const int2* __restrict__ csr, const int* __restrict__ rowptr,
    const int* __restrict__ cnt, const float* __restrict__ dinv,
    const float* __restrict__ b1, const float* __restrict__ Wp,
    float4* __restrict__ gout4, float* __restrict__ hp_part){
  extern __shared__ float hl[];   // 512 nodes x 32 feats = 64 KB
  int b = blockIdx.x;
  int xcd = b & 7, idx = b >> 3;
  int graph = xcd*8 + (idx >> 3);
  int sub = idx & 7;
  int qf = sub >> 1, half = sub & 1;
  int t = threadIdx.x;
  int gbase = graph*N0;
  int fp = t & 31;
  int f = qf*32 + fp;
  float wcol[10];
  #pragma unroll
  for (int k = 0; k < 10; k++) wcol[k] = W1[k*HID + f];
  for (int n = t >> 5; n < N0; n += 16){
    const float* xr = x + (gbase + n)*10;
    float acc = 0.f;
    #pragma unroll
    for (int k = 0; k < 10; k++) acc += xr[k]*wcol[k];
    hl[n*32 + fp] = acc;
  }
  __syncthreads();
  const float4* hl4 = (const float4*)hl;
  int l = t & 7, grp = t >> 3;
  float4 bb = ((const float4*)b1)[qf*8 + l];
  float4 wp = ((const float4*)Wp)[qf*8 + l];
  int n0 = half*256;
  for (int nl = n0 + grp; nl < n0 + 256; nl += 64){
    int node = gbase + nl;
    int start = rowptr[node], c = cnt[node];
    float4 acc = make_float4(0.f,0.f,0.f,0.f);
    int j = 0;
    for (; j + 4 <= c; j += 4){
      int2 e0 = csr[start+j],   e1 = csr[start+j+1];
      int2 e2 = csr[start+j+2], e3 = csr[start+j+3];
      float4 h0 = hl4[(e0.x - gbase)*8 + l];
      float4 h1 = hl4[(e1.x - gbase)*8 + l];
      float4 h2 = hl4[(e2.x - gbase)*8 + l];
      float4 h3 = hl4[(e3.x - gbase)*8 + l];
      float w0 = __int_as_float(e0.y), w1 = __int_as_float(e1.y);
      float w2 = __int_as_float(e2.y), w3 = __int_as_float(e3.y);
      acc.x += w0*h0.x + w1*h1.x + w2*h2.x + w3*h3.x;
      acc.y += w0*h0.y + w1*h1.y + w2*h2.y + w3*h3.y;
      acc.z += w0*h0.z + w1*h1.z + w2*h2.z + w3*h3.z;
      acc.w += w0*h0.w + w1*h1.w + w2*h2.w + w3*h3.w;
    }
    for (; j < c; j++){
      int2 e = csr[start + j];
      float wgt = __int_as_float(e.y);
      float4 hv = hl4[(e.x - gbase)*8 + l];
      acc.x += wgt*hv.x; acc.y += wgt*hv.y; acc.z += wgt*hv.z; acc.w += wgt*hv.w;
    }
    float di = dinv[node], dd = di*di;
    float4 hs = hl4[nl*8 + l];
    float4 v;
    v.x = fmaxf(acc.x + hs.x*dd + bb.x, 0.f);
    v.y = fmaxf(acc.y + hs.y*dd + bb.y, 0.f);
    v.z = fmaxf(acc.z + hs.z*dd + bb.z, 0.f);
    v.w = fmaxf(acc.w + hs.w*dd + bb.w, 0.f);
    gout4[node*32 + qf*8 + l] = v;
    float contrib = v.x*wp.x + v.y*wp.y + v.z*wp.z + v.w*wp.w;
    #pragma unroll
    for (int off = 4; off; off >>= 1) contrib += __shfl_down(contrib, off, 8);
    if (l == 0) hp_part[qf*32768 + node] = contrib;
  }
}

// h = pooled_x @ W, where pooled_x row j = gout_prev[si[j]] * sv[j] gathered
// on the fly (identical arithmetic to materializing xpool). 16 nodes per
// 128-thread block, XCD-pinned.
__global__ void k_gemm16p(const float* __restrict__ gprev,
                          const int* __restrict__ sig,
                          const float* __restrict__ svg,
                          const float* __restrict__ W,
                          float* __restrict__ out, int nprev, int nper){
  __shared__ float xr[16][HID];
  int b = blockIdx.x;
  int xcd = b & 7, idx = b >> 3, bpg = nper >> 4;
  int graph = xcd*8 + idx / bpg;
  int lb = (idx % bpg)*16;
  int f = threadIdx.x;
  #pragma unroll
  for (int nd = 0; nd < 16; nd++){
    int row  = sig[graph*512 + lb + nd];
    float val = svg[graph*512 + lb + nd];
    xr[nd][f] = gprev[(graph*nprev + row)*HID + f] * val;
  }
  __syncthreads();
  float acc[16];
  #pragma unroll
  for (int nd = 0; nd < 16; nd++) acc[nd] = 0.f;
  for (int i = 0; i < HID; i++){
    float wv = W[i*HID + f];
    #pragma unroll
    for (int nd = 0; nd < 16; nd++) acc[nd] += xr[nd][i]*wv;
  }
  #pragma unroll
  for (int nd = 0; nd < 16; nd++) out[(graph*nper + lb + nd)*HID + f] = acc[nd];
}

// gather GCN (levels 2/3), float4: 32 lanes per node-row, 8 nodes per block,
// 4-batched CSR loads. XCD-pinned. (round-0 verbatim)
__global__ __launch_bounds__(256) void k_gcn_gather(
    const float4* __restrict__ h4, const int2* __restrict__ csr,
    const int* __restrict__ rowptr, const int* __restrict__ cnt,
    const float* __restrict__ dinv, const float4* __restrict__ bias4,
    const float4* __restrict__ Wp4, float4* __restrict__ out4,
    float* __restrict__ hp, int nper){
  int b = blockIdx.x;
  int xcd = b & 7, idx = b >> 3, bpg = nper >> 3;
  int graph = xcd*8 + idx / bpg;
  int node = graph*nper + (idx % bpg)*8 + (threadIdx.x >> 5);
  int l = threadIdx.x & 31;
  int start = rowptr[node], c = cnt[node];
  float4 acc = make_float4(0.f, 0.f, 0.f, 0.f);
  int j = 0;
  for (; j + 4 <= c; j += 4){
    int2 e0 = csr[start+j],   e1 = csr[start+j+1];
    int2 e2 = csr[start+j+2], e3 = csr[start+j+3];
    float4 h0 = h4[e0.x*32 + l];
    float4 h1 = h4[e1.x*32 + l];
    float4 h2 = h4[e2.x*32 + l];
    float4 h3 = h4[e3.x*32 + l];
    float w0 = __int_as_float(e0.y), w1 = __int_as_float(e1.y);
    float w2 = __int_as_float(e2.y), w3 = __int_as_float(e3.y);
    acc.x += w0*h0.x + w1*h1.x + w2*h2.x + w3*h3.x;
    acc.y += w0*h0.y + w1*h1.y + w2*h2.y + w3*h3.y;
    acc.z += w0*h0.z + w1*h1.z + w2*h2.z + w3*h3.z;
    acc.w += w0*h0.w + w1*h1.w + w2*h2.w + w3*h3.w;
  }
  for (; j < c; j++){
    int2 e = csr[start + j];
    float wgt = __int_as_float(e.y);
    float4 hv = h4[e.x*32 + l];
    acc.x += wgt*hv.x; acc.y += wgt*hv.y; acc.z += wgt*hv.z; acc.w += wgt*hv.w;
  }
  float di = dinv[node], dd = di*di;
  float4 hs = h4[node*32 + l];
  float4 bb = bias4[l];
  float4 v;
  v.x = fmaxf(acc.x + hs.x*dd + bb.x, 0.f);
  v.y = fmaxf(acc.y + hs.y*dd + bb.y, 0.f);
  v.z = fmaxf(acc.z + hs.z*dd + bb.z, 0.f);
  v.w = fmaxf(acc.w + hs.w*dd + bb.w, 0.f);
  out4[node*32 + l] = v;
  float4 wp = Wp4[l];
  float contrib = v.x*wp.x + v.y*wp.y + v.z*wp.z + v.w*wp.w;
  #pragma unroll
  for (int off = 16; off; off >>= 1) contrib += __shfl_down(contrib, off, 32);
  if (l == 0) hp[node] = contrib;
}

// Per-graph mega, 1024 threads (4 waves/SIMD for latency hiding):
// split score (fixed-order partial combine) -> hybrid bitonic top-k ->
// readout (+ si/sv export; NO xpool write) -> relabel with shfl-scan.
// Last level: fused readout finalize + MLP + log_softmax.
__global__ __launch_bounds__(1024) void k_mega(
    const float4* __restrict__ gout4, const float* __restrict__ hp_part,
    int l1flag, const float* __restrict__ hp,
    int2* __restrict__ csr, int* __restrict__ rowptr, int* __restrict__ cnt,
    float* __restrict__ dinv, const float* __restrict__ bp,
    int2* __restrict__ edges, int* __restrict__ sig, float* __restrict__ svg,
    float* __restrict__ z, int nper, int lastlev,
    const float* __restrict__ L1W, const float* __restrict__ L1b,
    const float* __restrict__ L2W, const float* __restrict__ L2b,
    float* __restrict__ out){
  __shared__ float sv[512];
  __shared__ int   si[512];
  __shared__ float hpl[512];
  __shared__ float spart[1024];
  __shared__ int   map_[512];
  __shared__ int   sb[512];
  __shared__ int   cur[256];
  __shared__ float dl[256];
  __shared__ int   wsum[4];
  __shared__ float4 pmx[16][32];
  __shared__ float4 psm[16][32];
  __shared__ float zr[256];
  __shared__ float h1[128];
  __shared__ float h2[64];
  __shared__ float red[2];
  int g = (blockIdx.x & 7)*8 + (blockIdx.x >> 3);
  int t = threadIdx.x;
  int k = nper >> 1;
  int gbase = g*nper, ebase = g*EPG, gb2 = g*k;
  int SPL = 1024/nper;                    // 2, 4, 8
  int n = t & (nper-1), p = t / nper;
  bool act = t < nper;

  if (act){
    int node = gbase + t;
    hpl[t] = l1flag ? (hp_part[node] + hp_part[32768 + node] +
                       hp_part[65536 + node] + hp_part[98304 + node])
                    : hp[node];
  }
  __syncthreads();
  // split score-edge aggregation: part p of node n sums its contiguous chunk
  {
    int start = rowptr[gbase + n], c = cnt[gbase + n];
    int lo = (c*p)/SPL, hi = (c*(p+1))/SPL;
    float a = 0.f;
    for (int j = lo; j < hi; j++){
      int2 e = csr[start + j];
      a += __int_as_float(e.y)*hpl[e.x - gbase];
    }
    spart[t] = a;
  }
  __syncthreads();
  float v = 0.f; int idx = t;
  if (act){
    float a = 0.f;
    for (int pp = 0; pp < SPL; pp++) a += spart[t + pp*nper];
    float di = dinv[gbase + t];
    v = tanhf(a + hpl[t]*di*di + bp[0]);
  }
  // hybrid shfl/LDS bitonic (descending, idx tie-break)
  for (int kk = 2; kk <= nper; kk <<= 1){
    for (int jj = kk >> 1; jj > 0; jj >>= 1){
      if (jj >= 64){
        if (act){ sv[t] = v; si[t] = idx; }
        __syncthreads();
        if (act){
          int pr = t ^ jj;
          float pv = sv[pr]; int pi = si[pr];
          bool amLower = (t & jj) == 0;
          bool dirDesc = (t & kk) == 0;
          bool betterMine = (v > pv) || (v == pv && idx < pi);
          if ((amLower == dirDesc) != betterMine){ v = pv; idx = pi; }
        }
        __syncthreads();
      } else if (act){
        float pv = __shfl_xor(v, jj);
        int   pi = __shfl_xor(idx, jj);
        bool amLower = (t & jj) == 0;
        bool dirDesc = (t & kk) == 0;
        bool betterMine = (v > pv) || (v == pv && idx < pi);
        if ((amLower == dirDesc) != betterMine){ v = pv; idx = pi; }
      }
    }
  }
  if (act){ sv[t] = v; si[t] = idx; }
  __syncthreads();
  // readout over top-k rows (no xpool materialization); si/sv exported
  int l = t & 31, j0 = t >> 5;
  if (t < 512){
    float4 mx = make_float4(-INFINITY,-INFINITY,-INFINITY,-INFINITY);
    float4 sm = make_float4(0.f,0.f,0.f,0.f);
    for (int j = j0; j < k; j += 16){
      float val = sv[j]; int row = si[j];
      float4 hv = gout4[(gbase + row)*32 + l];
      float4 o = make_float4(hv.x*val, hv.y*val, hv.z*val, hv.w*val);
      mx.x = fmaxf(mx.x, o.x); mx.y = fmaxf(mx.y, o.y);
      mx.z = fmaxf(mx.z, o.z); mx.w = fmaxf(mx.w, o.w);
      sm.x += o.x; sm.y += o.y; sm.z += o.z; sm.w += o.w;
    }
    pmx[j0][l] = mx; psm[j0][l] = sm;
  }
  if (t < 512 && t < k && !lastlev){ sig[g*512 + t] = si[t]; svg[g*512 + t] = sv[t]; }
  __syncthreads();
  if (t < 32){
    float4 M = pmx[0][t], S = psm[0][t];
    #pragma unroll
    for (int q = 1; q < 16; q++){
      float4 m2 = pmx[q][t], s2 = psm[q][t];
      M.x = fmaxf(M.x, m2.x); M.y = fmaxf(M.y, m2.y);
      M.z = fmaxf(M.z, m2.z); M.w = fmaxf(M.w, m2.w);
      S.x += s2.x; S.y += s2.y; S.z += s2.z; S.w += s2.w;
    }
    float ki = 1.f/(float)k;
    float* zp = z + g*256;
    if (l1flag){                           // first level: store (no prior zero)
      zp[t*4+0] = M.x; zp[t*4+1] = M.y; zp[t*4+2] = M.z; zp[t*4+3] = M.w;
      zp[128+t*4+0] = S.x*ki; zp[128+t*4+1] = S.y*ki;
      zp[128+t*4+2] = S.z*ki; zp[128+t*4+3] = S.w*ki;
    } else if (!lastlev){
      zp[t*4+0] += M.x; zp[t*4+1] += M.y; zp[t*4+2] += M.z; zp[t*4+3] += M.w;
      zp[128+t*4+0] += S.x*ki; zp[128+t*4+1] += S.y*ki;
      zp[128+t*4+2] += S.z*ki; zp[128+t*4+3] += S.w*ki;
    } else {
      zr[t*4+0] = zp[t*4+0] + M.x; zr[t*4+1] = zp[t*4+1] + M.y;
      zr[t*4+2] = zp[t*4+2] + M.z; zr[t*4+3] = zp[t*4+3] + M.w;
      zr[128+t*4+0] = zp[128+t*4+0] + S.x*ki;
      zr[128+t*4+1] = zp[128+t*4+1] + S.y*ki;
      zr[128+t*4+2] = zp[128+t*4+2] + S.z*ki;
      zr[128+t*4+3] = zp[128+t*4+3] + S.w*ki;
    }
  }
  if (lastlev){
    __syncthreads();
    if (t < 128){
      float a = L1b[t];
      for (int i = 0; i < 256; i++) a += zr[i]*L1W[i*128 + t];
      h1[t] = fmaxf(a, 0.f);
    }
    __syncthreads();
    if (t < 64){
      float a = L2b[t];
      for (int i = 0; i < 128; i++) a += h1[i]*L2W[i*64 + t];
      h2[t] = fmaxf(a, 0.f);
    }
    __syncthreads();
    if (t == 0){
      float mxv = -INFINITY;
      for (int i = 0; i < 64; i++) mxv = fmaxf(mxv, h2[i]);
      float s = 0.f;
      for (int i = 0; i < 64; i++) s += expf(h2[i] - mxv);
      red[0] = mxv; red[1] = logf(s);
    }
    __syncthreads();
    if (t < 64) out[g*64 + t] = h2[t] - red[0] - red[1];
    return;
  }
  // relabel + next topology (1024 threads, 8 edge slots each; shfl-scan)
  if (act) map_[t] = -1;
  if (t < k) sb[t] = 0;
  __syncthreads();
  if (t < k) map_[si[t]] = t;
  __syncthreads();
  int2 ebuf[8];
  #pragma unroll
  for (int it = 0; it < 8; it++){
    int i = ebase + it*1024 + t;
    int2 e = edges[i];
    int2 ne = make_int2(-1, 0);
    if (e.x >= 0){
      int ns = map_[e.x - gbase], nd = map_[e.y - gbase];
      if (ns >= 0 && nd >= 0){
        ne = make_int2(gb2 + ns, gb2 + nd);
        atomicAdd(&sb[nd], 1);
      }
    }
    ebuf[it] = ne;
    edges[i] = ne;
  }
  __syncthreads();
  int vdeg = (t < k) ? sb[t] : 0;
  int lane = t & 63, wid = t >> 6;
  int x = vdeg;
  #pragma unroll
  for (int off = 1; off < 64; off <<= 1){
    int y = __shfl_up(x, off);
    if (lane >= off) x += y;
  }
  if (t < k && lane == 63) wsum[wid] = x;
  __syncthreads();
  if (t < k){
    int prefix = 0;
    #pragma unroll
    for (int wj = 0; wj < 4; wj++) prefix += (wj < wid) ? wsum[wj] : 0;
    int excl = x + prefix - vdeg;
    rowptr[gb2 + t] = ebase + excl;
    cnt[gb2 + t] = vdeg;
    cur[t] = excl;
    float dv = rsqrtf((float)vdeg + 1.f);
    dl[t] = dv;
    dinv[gb2 + t] = dv;
  }
  __syncthreads();
  #pragma unroll
  for (int it = 0; it < 8; it++){
    int2 e = ebuf[it];
    if (e.x >= 0){
      int sl = e.x - gb2, dc = e.y - gb2;
      int pos = atomicAdd(&cur[dc], 1);
      csr[ebase + pos] = make_int2(e.x, __float_as_int(dl[sl]*dl[dc]));
    }
  }
}

extern "C" void kernel_launch(void* const* d_in, const int* in_sizes, int n_in,
                              void* d_out, int out_size, void* d_ws, size_t ws_size,
                              hipStream_t stream){
  (void)in_sizes; (void)n_in; (void)out_size; (void)ws_size;
  const float* x0  = (const float*)d_in[0];
  const int*   s0  = (const int*)  d_in[1];
  const int*   d0  = (const int*)  d_in[2];
  const float* W1  = (const float*)d_in[3];  const float* b1 = (const float*)d_in[4];
  const float* W2  = (const float*)d_in[5];  const float* b2 = (const float*)d_in[6];
  const float* W3  = (const float*)d_in[7];  const float* b3 = (const float*)d_in[8];
  const float* Wp  = (const float*)d_in[9];  const float* bp = (const float*)d_in[10];
  const float* L1W = (const float*)d_in[11]; const float* L1b = (const float*)d_in[12];
  const float* L2W = (const float*)d_in[13]; const float* L2b = (const float*)d_in[14];
  float* out = (float*)d_out;

  // workspace layout (elements)
  float* w = (float*)d_ws;
  float* h     = w; w += 32768*HID;          // L2/L3 XW scratch
  float* gout  = w; w += 32768*HID;          // GCN output per level
  float* dinvv = w; w += 32768;
  float* hp    = w; w += 32768;
  float* hppt  = w; w += 4*32768;            // L1 hp quarter-partials
  float* z     = w; w += BGR*256;
  float* svg   = w; w += 32768;              // top-k scores (rank order)
  int* sig     = (int*)w; w += 32768;        // top-k node ids (rank order)
  int* cnt     = (int*)w; w += 32768;
  int* rowptr  = (int*)w; w += 32768;
  int2* edges  = (int2*)w; w += 2*E_TOT;
  int2* csr    = (int2*)w; w += 2*E_TOT;

  k_topo0<<<BGR, 512, 0, stream>>>(s0, d0, edges, cnt, rowptr, dinvv, csr);

  // level 1: 512 -> 256
  k_l1_fused<<<512, 512, 65536, stream>>>(x0, W1, csr, rowptr, cnt, dinvv,
                                          b1, Wp, (float4*)gout, hppt);
  k_mega<<<BGR, 1024, 0, stream>>>((const float4*)gout, hppt, 1, hp, csr,
                                   rowptr, cnt, dinvv, bp, edges, sig, svg,
                                   z, 512, 0, L1W, L1b, L2W, L2b, out);
  // level 2: 256 -> 128
  k_gemm16p<<<16384/16, HID, 0, stream>>>(gout, sig, svg, W2, h, 512, 256);
  k_gcn_gather<<<16384/8, 256, 0, stream>>>((const float4*)h, csr, rowptr, cnt,
                                            dinvv, (const float4*)b2,
                                            (const float4*)Wp, (float4*)gout,
                                            hp, 256);
  k_mega<<<BGR, 1024, 0, stream>>>((const float4*)gout, hppt, 0, hp, csr,
                                   rowptr, cnt, dinvv, bp, edges, sig, svg,
                                   z, 256, 0, L1W, L1b, L2W, L2b, out);
  // level 3: 128 -> 64 (+ fused readout/MLP/log_softmax)
  k_gemm16p<<<8192/16, HID, 0, stream>>>(gout, sig, svg, W3, h, 256, 128);
  k_gcn_gather<<<8192/8, 256, 0, stream>>>((const float4*)h, csr, rowptr, cnt,
                                           dinvv, (const float4*)b3,
                                           (const float4*)Wp, (float4*)gout,
                                           hp, 128);
  k_mega<<<BGR, 1024, 0, stream>>>((const float4*)gout, hppt, 0, hp, csr,
                                   rowptr, cnt, dinvv, bp, edges, sig, svg,
                                   z, 128, 1, L1W, L1b, L2W, L2b, out);
}